// Round 24
// baseline (96.120 us; speedup 1.0000x reference)
//
#include <hip/hip_runtime.h>
#include <math.h>

constexpr int CB   = 8;
constexpr int CN   = 2048;
constexpr int CD   = 8;
constexpr int CDEC = 128;
constexpr int CBN  = CB * CN;
constexpr int NWRD = CN / 64;   // 32 mask words per row
constexpr int JSP  = 32;        // j-split: part stays L2-resident
constexpr int JLEN = CN / JSP;  // 64

// per-lane bit select from a WAVE-UNIFORM mask (SGPR pair): 1 VALU op.
__device__ __forceinline__ float msel_s(unsigned long long m, float p) {
  float r;
  asm("v_cndmask_b32 %0, 0, %1, %2" : "=v"(r) : "v"(p), "s"(m));
  return r;
}

// ---- prep (R23 + cnt zeroing): h = xW, f1/f2, exps; pre-apply x@w1, x@b1 ----
__global__ void prep_k(const float* __restrict__ x,
                       const float* __restrict__ W, const float* __restrict__ a,
                       const float* __restrict__ w1, const float* __restrict__ b1,
                       float4* __restrict__ pk, float4* __restrict__ qk,
                       float* __restrict__ feat1w, float* __restrict__ selfb1,
                       int* __restrict__ cnt) {
  int t = blockIdx.x * blockDim.x + threadIdx.x;
  if (blockIdx.x == 0 && threadIdx.x < CB) cnt[threadIdx.x] = 0;  // per-launch reset
  if (t >= CBN) return;
  const float* xr = x + (size_t)t * CD;
  float h[CD];
#pragma unroll
  for (int d = 0; d < CD; ++d) {
    float s = 0.f;
#pragma unroll
    for (int k = 0; k < CD; ++k) s = fmaf(xr[k], W[k * CD + d], s);
    h[d] = s;
  }
  float s1 = 0.f, s2 = 0.f;
#pragma unroll
  for (int d = 0; d < CD; ++d) { s1 = fmaf(h[d], a[d], s1); s2 = fmaf(h[d], a[CD + d], s2); }
  pk[t] = make_float4(s1, expf(s1), expf(0.2f * s1), 0.f);
  qk[t] = make_float4(s2, expf(s2), expf(0.2f * s2), 0.f);
  float fw[8], fb[8];
#pragma unroll
  for (int o = 0; o < 8; ++o) {
    float sw = 0.f, sb = 0.f;
#pragma unroll
    for (int d = 0; d < CD; ++d) {
      sw = fmaf(xr[d], w1[d * 8 + o], sw);
      sb = fmaf(xr[d], b1[d * 8 + o], sb);
    }
    fw[o] = sw; fb[o] = sb;
  }
  float4* f4 = (float4*)(feat1w + (size_t)t * 8);
  f4[0] = make_float4(fw[0], fw[1], fw[2], fw[3]);
  f4[1] = make_float4(fw[4], fw[5], fw[6], fw[7]);
  float4* s4 = (float4*)(selfb1 + (size_t)t * 8);
  s4[0] = make_float4(fb[0], fb[1], fb[2], fb[3]);
  s4[1] = make_float4(fb[4], fb[5], fb[6], fb[7]);
}

// -- mask (R23 verbatim): unroll-4 word loop for 4x memory-level parallelism --
__global__ __launch_bounds__(256) void mask_k(const int* __restrict__ adj,
    float4* __restrict__ pk, const float4* __restrict__ qk,
    unsigned long long* __restrict__ maskT) {
  const int lane = threadIdx.x & 63;
  const int gw2 = blockIdx.x * 4 + (threadIdx.x >> 6);   // wave id [0,4096)
  const int b = gw2 >> 9;                                 // 512 waves per batch
  const int jw = gw2 & 511;                               // rows j = jw + 512r
  const int* ab = adj + (size_t)b * CN * CN;
  const float4* qb = qk + (size_t)b * CN;
  float f1[4];
#pragma unroll
  for (int r = 0; r < 4; ++r) f1[r] = pk[b * CN + jw + 512 * r].x;
  float A[4] = {0.f, 0.f, 0.f, 0.f}, C[4] = {0.f, 0.f, 0.f, 0.f};
  int deg[4] = {0, 0, 0, 0};
#pragma unroll 4
  for (int k = 0; k < NWRD; ++k) {    // unroll 4: 16 independent loads in flight
    int i = k * 64 + lane;
    float4 q = qb[i];                                     // loaded once, 4 rows
    unsigned long long m[4];
#pragma unroll
    for (int r = 0; r < 4; ++r) {
      bool bit = ab[(size_t)(jw + 512 * r) * CN + i] > 0;
      m[r] = __ballot(bit);
      bool cond = (f1[r] + q.x) >= 0.f;
      A[r] += (bit && cond) ? q.y : 0.f;
      C[r] += (bit && !cond) ? q.z : 0.f;
    }
    if (lane == 0) {
#pragma unroll
      for (int r = 0; r < 4; ++r) {
        maskT[((size_t)(b * NWRD + k)) * CN + jw + 512 * r] = m[r];
        deg[r] += __popcll(m[r]);
      }
    }
  }
#pragma unroll
  for (int r = 0; r < 4; ++r) {
#pragma unroll
    for (int off = 32; off; off >>= 1) {
      A[r] += __shfl_down(A[r], off);
      C[r] += __shfl_down(C[r], off);
    }
  }
  if (lane == 0) {
#pragma unroll
    for (int r = 0; r < 4; ++r) {
      int gr = b * CN + jw + 512 * r;
      float4 pj = pk[gr];
      float s = pj.y * A[r] + pj.z * C[r];
      float ga = (s > 0.f) ? pj.y / s : 0.f;
      float gb = (s > 0.f) ? pj.z / s : 0.f;
      float dv = 1.f / (float)(deg[r] + 1);
      pk[gr] = make_float4(pj.x, ga, gb, dv);
    }
  }
}

// --- fold-free aggregation (R23 verbatim): part = Σ_j attn[j,i]*feat[j,:] ---
__global__ __launch_bounds__(256) void aggf_k(const float* __restrict__ feat,
                      const unsigned long long* __restrict__ maskT,
                      const float4* __restrict__ pk, const float4* __restrict__ qk,
                      float* __restrict__ part) {
  const int js = blockIdx.x, ic = blockIdx.y, b = blockIdx.z;
  const int t = threadIdx.x;
  const int w = __builtin_amdgcn_readfirstlane(t >> 6);
  const int i1 = ic * 512 + t, i2 = i1 + 256;
  const int gi1 = b * CN + i1, gi2 = b * CN + i2;
  float4 q1 = qk[gi1], q2 = qk[gi2];
  const unsigned long long* mc1 = maskT + ((size_t)(b * NWRD + ic * 8 + w)) * CN + js * JLEN;
  const unsigned long long* mc2 = maskT + ((size_t)(b * NWRD + ic * 8 + 4 + w)) * CN + js * JLEN;
  const float4* pb = pk + (size_t)b * CN + js * JLEN;
  const float* fb  = feat + ((size_t)b * CN + js * JLEN) * 8;
  float acc1[8], acc2[8];
#pragma unroll
  for (int d = 0; d < 8; ++d) { acc1[d] = 0.f; acc2[d] = 0.f; }
#pragma unroll 4
  for (int jj = 0; jj < JLEN; ++jj) {
    unsigned long long m1 = mc1[jj];            // wave-uniform -> s_load (SGPR pair)
    unsigned long long m2 = mc2[jj];
    float4 pj = pb[jj];                         // uniform
    const float* fr = fb + jj * 8;              // uniform
    float wA = msel_s(m1, fmaxf(pj.y * q1.y, pj.z * q1.z));
    float wB = msel_s(m2, fmaxf(pj.y * q2.y, pj.z * q2.z));
#pragma unroll
    for (int d = 0; d < 8; ++d) {
      acc1[d] = fmaf(wA, fr[d], acc1[d]);
      acc2[d] = fmaf(wB, fr[d], acc2[d]);
    }
  }
  float4* p1 = (float4*)(part + ((size_t)js * CBN + gi1) * 8);
  float4* p2 = (float4*)(part + ((size_t)js * CBN + gi2) * 8);
  p1[0] = make_float4(acc1[0], acc1[1], acc1[2], acc1[3]);
  p1[1] = make_float4(acc1[4], acc1[5], acc1[6], acc1[7]);
  p2[0] = make_float4(acc2[0], acc2[1], acc2[2], acc2[3]);
  p2[1] = make_float4(acc2[4], acc2[5], acc2[6], acc2[7]);
}

// ---- epi8 (R23 verbatim): partials -> out1 row -> pre-apply layer-2 weights ----
__global__ void epi8_k(const float* __restrict__ part, const float* __restrict__ selfb1,
                       const float4* __restrict__ pk,
                       const float* __restrict__ w2, const float* __restrict__ b2,
                       float* __restrict__ feat2w, float* __restrict__ selfb2) {
  int t = blockIdx.x * blockDim.x + threadIdx.x;
  if (t >= CBN) return;
  float4 a0 = make_float4(0.f, 0.f, 0.f, 0.f), a1 = a0;
  for (int p_ = 0; p_ < JSP; ++p_) {
    const float4* pr = (const float4*)(part + ((size_t)p_ * CBN + t) * 8);
    float4 r0 = pr[0], r1 = pr[1];
    a0.x += r0.x; a0.y += r0.y; a0.z += r0.z; a0.w += r0.w;
    a1.x += r1.x; a1.y += r1.y; a1.z += r1.z; a1.w += r1.w;
  }
  float di = pk[t].w;
  const float4* sb = (const float4*)(selfb1 + (size_t)t * 8);
  float4 s0 = sb[0], s1 = sb[1];
  float c[16] = {a0.x * di, a0.y * di, a0.z * di, a0.w * di,
                 a1.x * di, a1.y * di, a1.z * di, a1.w * di,
                 s0.x, s0.y, s0.z, s0.w, s1.x, s1.y, s1.z, s1.w};
  float nn = 0.f;
#pragma unroll
  for (int k = 0; k < 16; ++k) nn += c[k] * c[k];
  float inv = 1.f / fmaxf(sqrtf(nn), 1e-12f);
  float ff[16];
#pragma unroll
  for (int k = 0; k < 16; ++k) {
    float v = c[k] * inv;
    ff[k] = (v >= 0.f) ? v : 0.1f * v;
  }
  float fw[8], fb[8];
#pragma unroll
  for (int o = 0; o < 8; ++o) {
    float sw = 0.f, sb2_ = 0.f;
#pragma unroll
    for (int d = 0; d < 16; ++d) {
      sw = fmaf(ff[d], w2[d * 8 + o], sw);
      sb2_ = fmaf(ff[d], b2[d * 8 + o], sb2_);
    }
    fw[o] = sw; fb[o] = sb2_;
  }
  float4* f4 = (float4*)(feat2w + (size_t)t * 8);
  f4[0] = make_float4(fw[0], fw[1], fw[2], fw[3]);
  f4[1] = make_float4(fw[4], fw[5], fw[6], fw[7]);
  float4* s4 = (float4*)(selfb2 + (size_t)t * 8);
  s4[0] = make_float4(fb[0], fb[1], fb[2], fb[3]);
  s4[1] = make_float4(fb[4], fb[5], fb[6], fb[7]);
}

// ==== epi16f + dec fused (R20-verified tail): last block per batch decodes ====
__global__ __launch_bounds__(256) void epi16fd_k(
    const float* __restrict__ part2, const float* __restrict__ selfb2,
    const unsigned long long* __restrict__ maskT,
    const float4* __restrict__ pk, const float4* __restrict__ qk,
    float* __restrict__ gpart, float* __restrict__ self2, int* __restrict__ cnt,
    const float* __restrict__ w3, const float* __restrict__ b3,
    const float* __restrict__ P1, const float* __restrict__ P2,
    float* __restrict__ y) {
  __shared__ float redA[4][16], redB[4][16];
  const int t = threadIdx.x;
  const int lane = t & 63, wv = t >> 6;
  const int gr = blockIdx.x * 256 + t;
  const int b = blockIdx.x >> 3, blk8 = blockIdx.x & 7;
  const int j = gr - b * CN;
  const int ia = CN - 2, ib = CN - 1;
  float4 a0 = make_float4(0.f, 0.f, 0.f, 0.f), a1 = a0;
  for (int p = 0; p < JSP; ++p) {
    const float4* pr = (const float4*)(part2 + ((size_t)p * CBN + gr) * 8);
    float4 r0 = pr[0], r1 = pr[1];
    a0.x += r0.x; a0.y += r0.y; a0.z += r0.z; a0.w += r0.w;
    a1.x += r1.x; a1.y += r1.y; a1.z += r1.z; a1.w += r1.w;
  }
  float4 pj = pk[gr];
  const float4* sb = (const float4*)(selfb2 + (size_t)gr * 8);
  float4 s0 = sb[0], s1 = sb[1];
  float c[16] = {a0.x * pj.w, a0.y * pj.w, a0.z * pj.w, a0.w * pj.w,
                 a1.x * pj.w, a1.y * pj.w, a1.z * pj.w, a1.w * pj.w,
                 s0.x, s0.y, s0.z, s0.w, s1.x, s1.y, s1.z, s1.w};
  float nn = 0.f;
#pragma unroll
  for (int k = 0; k < 16; ++k) nn += c[k] * c[k];
  float inv = 1.f / fmaxf(sqrtf(nn), 1e-12f);
  float ff[16];
#pragma unroll
  for (int k = 0; k < 16; ++k) {
    float v = c[k] * inv;
    ff[k] = (v >= 0.f) ? v : 0.1f * v;   // out2 row
  }
  if (j == ia || j == ib) {
    float* s = self2 + ((size_t)b * 2 + (j == ib ? 1 : 0)) * 16;
#pragma unroll
    for (int d = 0; d < 16; ++d) s[d] = ff[d];
  }
  unsigned long long m = maskT[((size_t)(b * NWRD + (NWRD - 1))) * CN + j];
  float4 qa = qk[b * CN + ia], qb = qk[b * CN + ib];
  float wA = ((m >> 62) & 1ull) ? fmaxf(pj.y * qa.y, pj.z * qa.z) : 0.f;
  float wB = (m >> 63) ? fmaxf(pj.y * qb.y, pj.z * qb.z) : 0.f;
  float accA[16], accB[16];
#pragma unroll
  for (int d = 0; d < 16; ++d) { accA[d] = wA * ff[d]; accB[d] = wB * ff[d]; }
#pragma unroll
  for (int d = 0; d < 16; ++d) {
#pragma unroll
    for (int off = 32; off; off >>= 1) {
      accA[d] += __shfl_down(accA[d], off);
      accB[d] += __shfl_down(accB[d], off);
    }
  }
  if (lane == 0) {
#pragma unroll
    for (int d = 0; d < 16; ++d) { redA[wv][d] = accA[d]; redB[wv][d] = accB[d]; }
  }
  __syncthreads();
  if (t < 32) {
    int row = t >> 4, k = t & 15;
    float s = row ? (redB[0][k] + redB[1][k] + redB[2][k] + redB[3][k])
                  : (redA[0][k] + redA[1][k] + redA[2][k] + redA[3][k]);
    gpart[(((size_t)b * 8 + blk8) * 2 + row) * 16 + k] = s;
  }
  // ---- last-block-done: 8th block of batch b runs the decoder ----
  __threadfence();
  __syncthreads();
  __shared__ int isLast;
  if (t == 0) isLast = (atomicAdd(&cnt[b], 1) == 7) ? 1 : 0;
  __syncthreads();
  if (!isLast) return;
  __threadfence();   // acquire: see all 8 blocks' gpart/self2
  __shared__ float agA[16], agB[16], cA[16], cB[16], daF[16], dbF[16];
  __shared__ float vsh[CDEC], red[CDEC];
  if (t < 32) {
    int row = t >> 4, k = t & 15;
    float s = 0.f;
#pragma unroll
    for (int blk = 0; blk < 8; ++blk)
      s += gpart[(((size_t)b * 8 + blk) * 2 + row) * 16 + k];
    float dv = pk[b * CN + (row ? ib : ia)].w;
    (row ? agB : agA)[k] = s * dv;
  }
  __syncthreads();
  if (t < 32) {
    int row = t >> 4, k = t & 15;
    const float* ag = row ? agB : agA;
    const float* self = self2 + ((size_t)b * 2 + row) * 16;
    float s = 0.f;
    if (k < 8) {
#pragma unroll
      for (int d = 0; d < 16; ++d) s = fmaf(ag[d], w3[d * 8 + k], s);
    } else {
#pragma unroll
      for (int d = 0; d < 16; ++d) s = fmaf(self[d], b3[d * 8 + (k - 8)], s);
    }
    (row ? cB : cA)[k] = s;
  }
  __syncthreads();
  if (t < 32) {
    int row = t >> 4, k = t & 15;
    const float* cc = row ? cB : cA;
    float nn2 = 0.f;
#pragma unroll
    for (int q = 0; q < 16; ++q) nn2 += cc[q] * cc[q];
    float inv2 = 1.f / fmaxf(sqrtf(nn2), 1e-12f);
    float v = cc[k] * inv2;
    (row ? dbF : daF)[k] = (v >= 0.f) ? v : 0.1f * v;
  }
  __syncthreads();
  float ue = 0.f, ve = 0.f;
  if (t < CDEC) {
#pragma unroll
    for (int i = 0; i < 16; ++i) {
      ue = fmaf(daF[i], P1[i * CDEC + t], ue);
      ve = fmaf(dbF[i], P1[i * CDEC + t], ve);
    }
    vsh[t] = ve;
  }
  __syncthreads();
  if (t < CDEC) {
    float s = 0.f;
    for (int e2 = 0; e2 < CDEC; ++e2) s = fmaf(P2[t * CDEC + e2], vsh[e2], s);
    red[t] = s * ue;
  }
  __syncthreads();
  for (int off = 64; off; off >>= 1) {
    if (t < off) red[t] += red[t + off];
    __syncthreads();
  }
  if (t == 0) y[b] = red[0];
}

extern "C" void kernel_launch(void* const* d_in, const int* in_sizes, int n_in,
                              void* d_out, int out_size, void* d_ws, size_t ws_size,
                              hipStream_t stream) {
  const float* x  = (const float*)d_in[0];
  const int*   adj = (const int*)d_in[1];
  const float* W  = (const float*)d_in[3];
  const float* a  = (const float*)d_in[4];
  const float* w1 = (const float*)d_in[5];
  const float* b1 = (const float*)d_in[6];
  const float* w2 = (const float*)d_in[7];
  const float* b2 = (const float*)d_in[8];
  const float* w3 = (const float*)d_in[9];
  const float* b3 = (const float*)d_in[10];
  const float* P1 = (const float*)d_in[11];
  const float* P2 = (const float*)d_in[12];
  float* y = (float*)d_out;

  char* base = (char*)d_ws;
  size_t off = 0;
  auto alloc = [&](size_t bytes) -> void* {
    void* r = base + off;
    off += (bytes + 255) & ~(size_t)255;
    return r;
  };
  float4* pk = (float4*)alloc(sizeof(float4) * CBN);
  float4* qk = (float4*)alloc(sizeof(float4) * CBN);
  unsigned long long* maskT =
      (unsigned long long*)alloc(sizeof(unsigned long long) * (size_t)CBN * NWRD);
  float* feat1w = (float*)alloc(sizeof(float) * (size_t)CBN * 8);
  float* selfb1 = (float*)alloc(sizeof(float) * (size_t)CBN * 8);
  float* feat2w = (float*)alloc(sizeof(float) * (size_t)CBN * 8);
  float* selfb2 = (float*)alloc(sizeof(float) * (size_t)CBN * 8);
  float* part   = (float*)alloc(sizeof(float) * (size_t)JSP * CBN * 8);  // 16.8 MB
  float* gpart  = (float*)alloc(sizeof(float) * CB * 8 * 2 * 16);
  float* self2  = (float*)alloc(sizeof(float) * CB * 2 * 16);
  int*   cnt    = (int*)alloc(sizeof(int) * CB);

  hipLaunchKernelGGL(prep_k, dim3(CBN / 256), dim3(256), 0, stream,
                     x, W, a, w1, b1, pk, qk, feat1w, selfb1, cnt);
  hipLaunchKernelGGL(mask_k, dim3(1024), dim3(256), 0, stream, adj, pk, qk, maskT);
  // layer 1 (aggregate x@w1, fold-free)
  hipLaunchKernelGGL(aggf_k, dim3(JSP, 4, CB), dim3(256), 0, stream, feat1w, maskT, pk, qk, part);
  hipLaunchKernelGGL(epi8_k, dim3(CBN / 256), dim3(256), 0, stream,
                     part, selfb1, pk, w2, b2, feat2w, selfb2);
  // layer 2 (aggregate out1@w2, fold-free; part reused)
  hipLaunchKernelGGL(aggf_k, dim3(JSP, 4, CB), dim3(256), 0, stream, feat2w, maskT, pk, qk, part);
  // layer 3 + decoder fused (last-block-done per batch)
  hipLaunchKernelGGL(epi16fd_k, dim3(CBN / 256), dim3(256), 0, stream,
                     part, selfb2, maskT, pk, qk, gpart, self2, cnt, w3, b3, P1, P2, y);
}

// Round 25
// 91.737 us; speedup vs baseline: 1.0478x; 1.0478x over previous
//
#include <hip/hip_runtime.h>
#include <math.h>

constexpr int CB   = 8;
constexpr int CN   = 2048;
constexpr int CD   = 8;
constexpr int CDEC = 128;
constexpr int CBN  = CB * CN;
constexpr int NWRD = CN / 64;   // 32 mask words per row
constexpr int JSP  = 32;        // j-split: part stays L2-resident
constexpr int JLEN = CN / JSP;  // 64

// per-lane bit select from a WAVE-UNIFORM mask (SGPR pair): 1 VALU op.
__device__ __forceinline__ float msel_s(unsigned long long m, float p) {
  float r;
  asm("v_cndmask_b32 %0, 0, %1, %2" : "=v"(r) : "v"(p), "s"(m));
  return r;
}

// ---- prep: h = xW, f1/f2, exps; pre-apply layer-1 weights: x@w1, x@b1 ----
__global__ void prep_k(const float* __restrict__ x,
                       const float* __restrict__ W, const float* __restrict__ a,
                       const float* __restrict__ w1, const float* __restrict__ b1,
                       float4* __restrict__ pk, float4* __restrict__ qk,
                       float* __restrict__ feat1w, float* __restrict__ selfb1) {
  int t = blockIdx.x * blockDim.x + threadIdx.x;
  if (t >= CBN) return;
  const float* xr = x + (size_t)t * CD;
  float h[CD];
#pragma unroll
  for (int d = 0; d < CD; ++d) {
    float s = 0.f;
#pragma unroll
    for (int k = 0; k < CD; ++k) s = fmaf(xr[k], W[k * CD + d], s);
    h[d] = s;
  }
  float s1 = 0.f, s2 = 0.f;
#pragma unroll
  for (int d = 0; d < CD; ++d) { s1 = fmaf(h[d], a[d], s1); s2 = fmaf(h[d], a[CD + d], s2); }
  pk[t] = make_float4(s1, expf(s1), expf(0.2f * s1), 0.f);
  qk[t] = make_float4(s2, expf(s2), expf(0.2f * s2), 0.f);
  float fw[8], fb[8];
#pragma unroll
  for (int o = 0; o < 8; ++o) {
    float sw = 0.f, sb = 0.f;
#pragma unroll
    for (int d = 0; d < CD; ++d) {
      sw = fmaf(xr[d], w1[d * 8 + o], sw);
      sb = fmaf(xr[d], b1[d * 8 + o], sb);
    }
    fw[o] = sw; fb[o] = sb;
  }
  float4* f4 = (float4*)(feat1w + (size_t)t * 8);
  f4[0] = make_float4(fw[0], fw[1], fw[2], fw[3]);
  f4[1] = make_float4(fw[4], fw[5], fw[6], fw[7]);
  float4* s4 = (float4*)(selfb1 + (size_t)t * 8);
  s4[0] = make_float4(fb[0], fb[1], fb[2], fb[3]);
  s4[1] = make_float4(fb[4], fb[5], fb[6], fb[7]);
}

// -- mask: unroll-4 word loop for 4x memory-level parallelism (R23 verbatim) --
__global__ __launch_bounds__(256) void mask_k(const int* __restrict__ adj,
    float4* __restrict__ pk, const float4* __restrict__ qk,
    unsigned long long* __restrict__ maskT) {
  const int lane = threadIdx.x & 63;
  const int gw2 = blockIdx.x * 4 + (threadIdx.x >> 6);   // wave id [0,4096)
  const int b = gw2 >> 9;                                 // 512 waves per batch
  const int jw = gw2 & 511;                               // rows j = jw + 512r
  const int* ab = adj + (size_t)b * CN * CN;
  const float4* qb = qk + (size_t)b * CN;
  float f1[4];
#pragma unroll
  for (int r = 0; r < 4; ++r) f1[r] = pk[b * CN + jw + 512 * r].x;
  float A[4] = {0.f, 0.f, 0.f, 0.f}, C[4] = {0.f, 0.f, 0.f, 0.f};
  int deg[4] = {0, 0, 0, 0};
#pragma unroll 4
  for (int k = 0; k < NWRD; ++k) {    // unroll 4: 16 independent loads in flight
    int i = k * 64 + lane;
    float4 q = qb[i];                                     // loaded once, 4 rows
    unsigned long long m[4];
#pragma unroll
    for (int r = 0; r < 4; ++r) {
      bool bit = ab[(size_t)(jw + 512 * r) * CN + i] > 0;
      m[r] = __ballot(bit);
      bool cond = (f1[r] + q.x) >= 0.f;
      A[r] += (bit && cond) ? q.y : 0.f;
      C[r] += (bit && !cond) ? q.z : 0.f;
    }
    if (lane == 0) {
#pragma unroll
      for (int r = 0; r < 4; ++r) {
        maskT[((size_t)(b * NWRD + k)) * CN + jw + 512 * r] = m[r];
        deg[r] += __popcll(m[r]);
      }
    }
  }
#pragma unroll
  for (int r = 0; r < 4; ++r) {
#pragma unroll
    for (int off = 32; off; off >>= 1) {
      A[r] += __shfl_down(A[r], off);
      C[r] += __shfl_down(C[r], off);
    }
  }
  if (lane == 0) {
#pragma unroll
    for (int r = 0; r < 4; ++r) {
      int gr = b * CN + jw + 512 * r;
      float4 pj = pk[gr];
      float s = pj.y * A[r] + pj.z * C[r];
      float ga = (s > 0.f) ? pj.y / s : 0.f;
      float gb = (s > 0.f) ? pj.z / s : 0.f;
      float dv = 1.f / (float)(deg[r] + 1);
      pk[gr] = make_float4(pj.x, ga, gb, dv);
    }
  }
}

// --- fold-free aggregation (R23 verbatim): part = Σ_j attn[j,i]*feat[j,:] ---
__global__ __launch_bounds__(256) void aggf_k(const float* __restrict__ feat,
                      const unsigned long long* __restrict__ maskT,
                      const float4* __restrict__ pk, const float4* __restrict__ qk,
                      float* __restrict__ part) {
  const int js = blockIdx.x, ic = blockIdx.y, b = blockIdx.z;
  const int t = threadIdx.x;
  const int w = __builtin_amdgcn_readfirstlane(t >> 6);
  const int i1 = ic * 512 + t, i2 = i1 + 256;
  const int gi1 = b * CN + i1, gi2 = b * CN + i2;
  float4 q1 = qk[gi1], q2 = qk[gi2];
  const unsigned long long* mc1 = maskT + ((size_t)(b * NWRD + ic * 8 + w)) * CN + js * JLEN;
  const unsigned long long* mc2 = maskT + ((size_t)(b * NWRD + ic * 8 + 4 + w)) * CN + js * JLEN;
  const float4* pb = pk + (size_t)b * CN + js * JLEN;
  const float* fb  = feat + ((size_t)b * CN + js * JLEN) * 8;
  float acc1[8], acc2[8];
#pragma unroll
  for (int d = 0; d < 8; ++d) { acc1[d] = 0.f; acc2[d] = 0.f; }
#pragma unroll 4
  for (int jj = 0; jj < JLEN; ++jj) {
    unsigned long long m1 = mc1[jj];            // wave-uniform -> s_load (SGPR pair)
    unsigned long long m2 = mc2[jj];
    float4 pj = pb[jj];                         // uniform
    const float* fr = fb + jj * 8;              // uniform
    float wA = msel_s(m1, fmaxf(pj.y * q1.y, pj.z * q1.z));
    float wB = msel_s(m2, fmaxf(pj.y * q2.y, pj.z * q2.z));
#pragma unroll
    for (int d = 0; d < 8; ++d) {
      acc1[d] = fmaf(wA, fr[d], acc1[d]);
      acc2[d] = fmaf(wB, fr[d], acc2[d]);
    }
  }
  float4* p1 = (float4*)(part + ((size_t)js * CBN + gi1) * 8);
  float4* p2 = (float4*)(part + ((size_t)js * CBN + gi2) * 8);
  p1[0] = make_float4(acc1[0], acc1[1], acc1[2], acc1[3]);
  p1[1] = make_float4(acc1[4], acc1[5], acc1[6], acc1[7]);
  p2[0] = make_float4(acc2[0], acc2[1], acc2[2], acc2[3]);
  p2[1] = make_float4(acc2[4], acc2[5], acc2[6], acc2[7]);
}

// ---- epi8 (R23 verbatim): partials -> out1 row -> pre-apply layer-2 weights ----
__global__ void epi8_k(const float* __restrict__ part, const float* __restrict__ selfb1,
                       const float4* __restrict__ pk,
                       const float* __restrict__ w2, const float* __restrict__ b2,
                       float* __restrict__ feat2w, float* __restrict__ selfb2) {
  int t = blockIdx.x * blockDim.x + threadIdx.x;
  if (t >= CBN) return;
  float4 a0 = make_float4(0.f, 0.f, 0.f, 0.f), a1 = a0;
  for (int p_ = 0; p_ < JSP; ++p_) {
    const float4* pr = (const float4*)(part + ((size_t)p_ * CBN + t) * 8);
    float4 r0 = pr[0], r1 = pr[1];
    a0.x += r0.x; a0.y += r0.y; a0.z += r0.z; a0.w += r0.w;
    a1.x += r1.x; a1.y += r1.y; a1.z += r1.z; a1.w += r1.w;
  }
  float di = pk[t].w;
  const float4* sb = (const float4*)(selfb1 + (size_t)t * 8);
  float4 s0 = sb[0], s1 = sb[1];
  float c[16] = {a0.x * di, a0.y * di, a0.z * di, a0.w * di,
                 a1.x * di, a1.y * di, a1.z * di, a1.w * di,
                 s0.x, s0.y, s0.z, s0.w, s1.x, s1.y, s1.z, s1.w};
  float nn = 0.f;
#pragma unroll
  for (int k = 0; k < 16; ++k) nn += c[k] * c[k];
  float inv = 1.f / fmaxf(sqrtf(nn), 1e-12f);
  float ff[16];
#pragma unroll
  for (int k = 0; k < 16; ++k) {
    float v = c[k] * inv;
    ff[k] = (v >= 0.f) ? v : 0.1f * v;
  }
  float fw[8], fb[8];
#pragma unroll
  for (int o = 0; o < 8; ++o) {
    float sw = 0.f, sb2_ = 0.f;
#pragma unroll
    for (int d = 0; d < 16; ++d) {
      sw = fmaf(ff[d], w2[d * 8 + o], sw);
      sb2_ = fmaf(ff[d], b2[d * 8 + o], sb2_);
    }
    fw[o] = sw; fb[o] = sb2_;
  }
  float4* f4 = (float4*)(feat2w + (size_t)t * 8);
  f4[0] = make_float4(fw[0], fw[1], fw[2], fw[3]);
  f4[1] = make_float4(fw[4], fw[5], fw[6], fw[7]);
  float4* s4 = (float4*)(selfb2 + (size_t)t * 8);
  s4[0] = make_float4(fb[0], fb[1], fb[2], fb[3]);
  s4[1] = make_float4(fb[4], fb[5], fb[6], fb[7]);
}

// ---- epi16f (R23 verbatim): out2 row in registers + layer-3 partial fold ----
__global__ __launch_bounds__(256) void epi16f_k(
    const float* __restrict__ part2, const float* __restrict__ selfb2,
    const unsigned long long* __restrict__ maskT,
    const float4* __restrict__ pk, const float4* __restrict__ qk,
    float* __restrict__ gpart, float* __restrict__ self2) {
  __shared__ float redA[4][16], redB[4][16];
  const int t = threadIdx.x;
  const int lane = t & 63, wv = t >> 6;
  const int gr = blockIdx.x * 256 + t;
  const int b = blockIdx.x >> 3, blk8 = blockIdx.x & 7;
  const int j = gr - b * CN;
  const int ia = CN - 2, ib = CN - 1;
  float4 a0 = make_float4(0.f, 0.f, 0.f, 0.f), a1 = a0;
  for (int p = 0; p < JSP; ++p) {
    const float4* pr = (const float4*)(part2 + ((size_t)p * CBN + gr) * 8);
    float4 r0 = pr[0], r1 = pr[1];
    a0.x += r0.x; a0.y += r0.y; a0.z += r0.z; a0.w += r0.w;
    a1.x += r1.x; a1.y += r1.y; a1.z += r1.z; a1.w += r1.w;
  }
  float4 pj = pk[gr];
  const float4* sb = (const float4*)(selfb2 + (size_t)gr * 8);
  float4 s0 = sb[0], s1 = sb[1];
  float c[16] = {a0.x * pj.w, a0.y * pj.w, a0.z * pj.w, a0.w * pj.w,
                 a1.x * pj.w, a1.y * pj.w, a1.z * pj.w, a1.w * pj.w,
                 s0.x, s0.y, s0.z, s0.w, s1.x, s1.y, s1.z, s1.w};
  float nn = 0.f;
#pragma unroll
  for (int k = 0; k < 16; ++k) nn += c[k] * c[k];
  float inv = 1.f / fmaxf(sqrtf(nn), 1e-12f);
  float ff[16];
#pragma unroll
  for (int k = 0; k < 16; ++k) {
    float v = c[k] * inv;
    ff[k] = (v >= 0.f) ? v : 0.1f * v;   // out2 row
  }
  if (j == ia || j == ib) {
    float* s = self2 + ((size_t)b * 2 + (j == ib ? 1 : 0)) * 16;
#pragma unroll
    for (int d = 0; d < 16; ++d) s[d] = ff[d];
  }
  unsigned long long m = maskT[((size_t)(b * NWRD + (NWRD - 1))) * CN + j];
  float4 qa = qk[b * CN + ia], qb = qk[b * CN + ib];
  float wA = ((m >> 62) & 1ull) ? fmaxf(pj.y * qa.y, pj.z * qa.z) : 0.f;
  float wB = (m >> 63) ? fmaxf(pj.y * qb.y, pj.z * qb.z) : 0.f;
  float accA[16], accB[16];
#pragma unroll
  for (int d = 0; d < 16; ++d) { accA[d] = wA * ff[d]; accB[d] = wB * ff[d]; }
#pragma unroll
  for (int d = 0; d < 16; ++d) {
#pragma unroll
    for (int off = 32; off; off >>= 1) {
      accA[d] += __shfl_down(accA[d], off);
      accB[d] += __shfl_down(accB[d], off);
    }
  }
  if (lane == 0) {
#pragma unroll
    for (int d = 0; d < 16; ++d) { redA[wv][d] = accA[d]; redB[wv][d] = accB[d]; }
  }
  __syncthreads();
  if (t < 32) {
    int row = t >> 4, k = t & 15;
    float s = row ? (redB[0][k] + redB[1][k] + redB[2][k] + redB[3][k])
                  : (redA[0][k] + redA[1][k] + redA[2][k] + redA[3][k]);
    gpart[(((size_t)b * 8 + blk8) * 2 + row) * 16 + k] = s;
  }
}

// ---- dec (R23 verbatim): reduce gpart, w3/b3, norm, leaky, bilinear ----
__global__ __launch_bounds__(CDEC) void dec_k(
    const float* __restrict__ gpart, const float* __restrict__ self2,
    const float4* __restrict__ pk,
    const float* __restrict__ w3, const float* __restrict__ b3,
    const float* __restrict__ P1, const float* __restrict__ P2,
    float* __restrict__ y) {
  __shared__ float agA[16], agB[16], cA[16], cB[16], daF[16], dbF[16];
  __shared__ float vsh[CDEC], red[CDEC];
  const int b = blockIdx.x;
  const int t = threadIdx.x;
  const int ia = CN - 2, ib = CN - 1;
  if (t < 32) {
    int row = t >> 4, k = t & 15;
    float s = 0.f;
#pragma unroll
    for (int blk = 0; blk < 8; ++blk)
      s += gpart[(((size_t)b * 8 + blk) * 2 + row) * 16 + k];
    float dv = pk[b * CN + (row ? ib : ia)].w;
    (row ? agB : agA)[k] = s * dv;
  }
  __syncthreads();
  if (t < 32) {
    int row = t >> 4, k = t & 15;
    const float* ag = row ? agB : agA;
    const float* self = self2 + ((size_t)b * 2 + row) * 16;
    float s = 0.f;
    if (k < 8) {
#pragma unroll
      for (int d = 0; d < 16; ++d) s = fmaf(ag[d], w3[d * 8 + k], s);
    } else {
#pragma unroll
      for (int d = 0; d < 16; ++d) s = fmaf(self[d], b3[d * 8 + (k - 8)], s);
    }
    (row ? cB : cA)[k] = s;
  }
  __syncthreads();
  if (t < 32) {
    int row = t >> 4, k = t & 15;
    const float* c = row ? cB : cA;
    float nn = 0.f;
#pragma unroll
    for (int q = 0; q < 16; ++q) nn += c[q] * c[q];
    float inv = 1.f / fmaxf(sqrtf(nn), 1e-12f);
    float v = c[k] * inv;
    (row ? dbF : daF)[k] = (v >= 0.f) ? v : 0.1f * v;
  }
  __syncthreads();
  float ue = 0.f, ve = 0.f;
#pragma unroll
  for (int i = 0; i < 16; ++i) {
    ue = fmaf(daF[i], P1[i * CDEC + t], ue);
    ve = fmaf(dbF[i], P1[i * CDEC + t], ve);
  }
  vsh[t] = ve;
  __syncthreads();
  float s = 0.f;
  for (int e2 = 0; e2 < CDEC; ++e2) s = fmaf(P2[t * CDEC + e2], vsh[e2], s);
  red[t] = s * ue;
  __syncthreads();
  for (int off = 64; off; off >>= 1) {
    if (t < off) red[t] += red[t + off];
    __syncthreads();
  }
  if (t == 0) y[b] = red[0];
}

extern "C" void kernel_launch(void* const* d_in, const int* in_sizes, int n_in,
                              void* d_out, int out_size, void* d_ws, size_t ws_size,
                              hipStream_t stream) {
  const float* x  = (const float*)d_in[0];
  const int*   adj = (const int*)d_in[1];
  const float* W  = (const float*)d_in[3];
  const float* a  = (const float*)d_in[4];
  const float* w1 = (const float*)d_in[5];
  const float* b1 = (const float*)d_in[6];
  const float* w2 = (const float*)d_in[7];
  const float* b2 = (const float*)d_in[8];
  const float* w3 = (const float*)d_in[9];
  const float* b3 = (const float*)d_in[10];
  const float* P1 = (const float*)d_in[11];
  const float* P2 = (const float*)d_in[12];
  float* y = (float*)d_out;

  char* base = (char*)d_ws;
  size_t off = 0;
  auto alloc = [&](size_t bytes) -> void* {
    void* r = base + off;
    off += (bytes + 255) & ~(size_t)255;
    return r;
  };
  float4* pk = (float4*)alloc(sizeof(float4) * CBN);
  float4* qk = (float4*)alloc(sizeof(float4) * CBN);
  unsigned long long* maskT =
      (unsigned long long*)alloc(sizeof(unsigned long long) * (size_t)CBN * NWRD);
  float* feat1w = (float*)alloc(sizeof(float) * (size_t)CBN * 8);
  float* selfb1 = (float*)alloc(sizeof(float) * (size_t)CBN * 8);
  float* feat2w = (float*)alloc(sizeof(float) * (size_t)CBN * 8);
  float* selfb2 = (float*)alloc(sizeof(float) * (size_t)CBN * 8);
  float* part   = (float*)alloc(sizeof(float) * (size_t)JSP * CBN * 8);  // 16.8 MB
  float* gpart  = (float*)alloc(sizeof(float) * CB * 8 * 2 * 16);
  float* self2  = (float*)alloc(sizeof(float) * CB * 2 * 16);

  hipLaunchKernelGGL(prep_k, dim3(CBN / 256), dim3(256), 0, stream,
                     x, W, a, w1, b1, pk, qk, feat1w, selfb1);
  hipLaunchKernelGGL(mask_k, dim3(1024), dim3(256), 0, stream, adj, pk, qk, maskT);
  // layer 1 (aggregate x@w1, fold-free)
  hipLaunchKernelGGL(aggf_k, dim3(JSP, 4, CB), dim3(256), 0, stream, feat1w, maskT, pk, qk, part);
  hipLaunchKernelGGL(epi8_k, dim3(CBN / 256), dim3(256), 0, stream,
                     part, selfb1, pk, w2, b2, feat2w, selfb2);
  // layer 2 (aggregate out1@w2, fold-free; part reused)
  hipLaunchKernelGGL(aggf_k, dim3(JSP, 4, CB), dim3(256), 0, stream, feat2w, maskT, pk, qk, part);
  // layer 3 folded into wide epi16f + tiny dec
  hipLaunchKernelGGL(epi16f_k, dim3(CBN / 256), dim3(256), 0, stream,
                     part, selfb2, maskT, pk, qk, gpart, self2);
  hipLaunchKernelGGL(dec_k, dim3(CB), dim3(CDEC), 0, stream,
                     gpart, self2, pk, w3, b3, P1, P2, y);
}